// Round 9
// baseline (176.508 us; speedup 1.0000x reference)
//
#include <hip/hip_runtime.h>
#include <math.h>

#define Bn 4
#define Cn 256
#define Nn 1024
#define Hn 8
#define Dn 32
#define BHND (Bn * Hn * Nn * Dn)   // 1048576
#define BHN  (Bn * Hn * Nn)        // 32768

typedef short bf16x8 __attribute__((ext_vector_type(8)));
typedef float f32x4 __attribute__((ext_vector_type(4)));

__device__ inline unsigned f2bf_rn_bits(float x) {
  union { float f; unsigned u; } v; v.f = x;
  return (v.u + 0x7FFFu + ((v.u >> 16) & 1u)) >> 16;
}
__device__ inline float bfbits2f(unsigned b) {
  union { unsigned u; float f; } v; v.u = b << 16; return v.f;
}
__device__ inline void split_bf(float x, unsigned& hi, unsigned& lo) {
  hi = f2bf_rn_bits(x);
  lo = f2bf_rn_bits(x - bfbits2f(hi));
}
// truncation split (cheaper; lo absorbs hi error, ~2^-16 rel)
__device__ inline unsigned split_bf_trunc_pack(float x) {
  union { float f; unsigned u; } v; v.f = x;
  unsigned hi = v.u >> 16;
  union { unsigned u; float f; } hv; hv.u = hi << 16;
  union { float f; unsigned u; } r; r.f = x - hv.f;
  return hi | (r.u & 0xffff0000u);
}
__device__ inline void unpack_u32x8(const uint4& a, const uint4& b, bf16x8& hi, bf16x8& lo) {
  int4 h4, l4;
  h4.x = (int)((a.x & 0xffffu) | (a.y << 16));  l4.x = (int)((a.x >> 16) | (a.y & 0xffff0000u));
  h4.y = (int)((a.z & 0xffffu) | (a.w << 16));  l4.y = (int)((a.z >> 16) | (a.w & 0xffff0000u));
  h4.z = (int)((b.x & 0xffffu) | (b.y << 16));  l4.z = (int)((b.x >> 16) | (b.y & 0xffff0000u));
  h4.w = (int)((b.z & 0xffffu) | (b.w << 16));  l4.w = (int)((b.z >> 16) | (b.w & 0xffff0000u));
  hi = *(bf16x8*)&h4; lo = *(bf16x8*)&l4;
}

// ---------------- K0: fused root dispatch ----------------
// blocks [0,32):    prior partial sums (8 chunks of 128 n per b)
// blocks [32,224):  transpose+split w_qkv [C,3C] -> wt hi/lo [3C,C]
// blocks [224,288): transpose+split w_proj [C,C] -> wpt hi/lo [C,C]
__global__ __launch_bounds__(256) void k_pre(const float* __restrict__ w,
                                             const float* __restrict__ wp,
                                             const float* __restrict__ dap,
                                             short* __restrict__ wt_h,
                                             short* __restrict__ wt_l,
                                             short* __restrict__ wpt_h,
                                             short* __restrict__ wpt_l,
                                             float* __restrict__ pp) {
  __shared__ float tile[32][33];
  int bi = blockIdx.x;
  if (bi < 32) {
    int b = bi >> 3, ch = bi & 7;
    int c = threadIdx.x;
    float s = 0.f;
    int n0 = ch * 128;
    for (int n = n0; n < n0 + 128; ++n) s += dap[(size_t)(b * Nn + n) * Cn + c];
    pp[(size_t)bi * Cn + c] = s;
  } else if (bi < 224) {
    int wi = bi - 32;
    int j0 = (wi >> 3) << 5;   // 0..736
    int k0 = (wi & 7) << 5;    // 0..224
    int tx = threadIdx.x & 31, ty = threadIdx.x >> 5;
#pragma unroll
    for (int i = 0; i < 4; ++i)
      tile[ty + i * 8][tx] = w[(size_t)(k0 + ty + i * 8) * 768 + j0 + tx];
    __syncthreads();
#pragma unroll
    for (int i = 0; i < 4; ++i) {
      float v = tile[tx][ty + i * 8];
      unsigned hb, lb; split_bf(v, hb, lb);
      wt_h[(size_t)(j0 + ty + i * 8) * 256 + k0 + tx] = (short)hb;
      wt_l[(size_t)(j0 + ty + i * 8) * 256 + k0 + tx] = (short)lb;
    }
  } else {
    int wi = bi - 224;
    int j0 = (wi >> 3) << 5;   // 0..224
    int k0 = (wi & 7) << 5;    // 0..224
    int tx = threadIdx.x & 31, ty = threadIdx.x >> 5;
#pragma unroll
    for (int i = 0; i < 4; ++i)
      tile[ty + i * 8][tx] = wp[(size_t)(k0 + ty + i * 8) * 256 + j0 + tx];
    __syncthreads();
#pragma unroll
    for (int i = 0; i < 4; ++i) {
      float v = tile[tx][ty + i * 8];
      unsigned hb, lb; split_bf(v, hb, lb);
      wpt_h[(size_t)(j0 + ty + i * 8) * 256 + k0 + tx] = (short)hb;
      wpt_l[(size_t)(j0 + ty + i * 8) * 256 + k0 + tx] = (short)lb;
    }
  }
}

// ---------------- K2: prep (diag*x*prior + x) + LayerNorm -> bf16 hi/lo -------
__global__ __launch_bounds__(256) void k_prep_ln(const float* __restrict__ ne,
                                                 const float* __restrict__ eg,
                                                 const float* __restrict__ pp,
                                                 const float* __restrict__ gamma,
                                                 const float* __restrict__ beta,
                                                 short* __restrict__ ln_h,
                                                 short* __restrict__ ln_l) {
  int bn = blockIdx.x;
  int b = bn >> 10, n = bn & 1023;
  int c = threadIdx.x;
  float x = ne[(size_t)(b * Cn + c) * Nn + n];
  float pr = 0.f;
#pragma unroll
  for (int ch = 0; ch < 8; ++ch) pr += pp[(size_t)(b * 8 + ch) * Cn + c];
  float dg = eg[(size_t)(b * Nn + n) * Nn + n];
  float x2 = x * (1.f + dg * pr);
  float s = x2, qq = x2 * x2;
#pragma unroll
  for (int off = 32; off >= 1; off >>= 1) {
    s += __shfl_xor(s, off);
    qq += __shfl_xor(qq, off);
  }
  __shared__ float ss[4], sq[4];
  if ((c & 63) == 0) { ss[c >> 6] = s; sq[c >> 6] = qq; }
  __syncthreads();
  s = ss[0] + ss[1] + ss[2] + ss[3];
  qq = sq[0] + sq[1] + sq[2] + sq[3];
  float mu = s * (1.f / 256.f);
  float var = qq * (1.f / 256.f) - mu * mu;
  float r = rsqrtf(var + 1e-5f);
  float v = (x2 - mu) * r * gamma[c] + beta[c];
  unsigned hb, lb; split_bf(v, hb, lb);
  ln_h[(size_t)bn * Cn + c] = (short)hb;
  ln_l[(size_t)bn * Cn + c] = (short)lb;
}

// ---------------- K3: QKV GEMM via split-bf16 MFMA, LDS-staged tiles ----------
__global__ __launch_bounds__(256) void k_qkv_mfma(
    const short* __restrict__ ln_h, const short* __restrict__ ln_l,
    const short* __restrict__ wt_h, const short* __restrict__ wt_l,
    short* __restrict__ q_hi, short* __restrict__ q_lo,
    short* __restrict__ k_hi, short* __restrict__ k_lo,
    short* __restrict__ vt_hi, short* __restrict__ vt_lo) {
  __shared__ short Ah[64 * 40];
  __shared__ short Al[64 * 40];
  __shared__ short Bh[64 * 40];
  __shared__ short Bl[64 * 40];
  __shared__ float ct[64][65];
  int m0 = blockIdx.x * 64;
  int j0 = blockIdx.y * 64;
  int t = threadIdx.x, wid = t >> 6, l = t & 63;
  int lr = l & 15, lq = l >> 4;
  f32x4 acc[4] = {};
  int row = t >> 2, ch = (t & 3) * 8;
  const short* a_h_src = ln_h + (size_t)(m0 + row) * 256 + ch;
  const short* a_l_src = ln_l + (size_t)(m0 + row) * 256 + ch;
  const short* b_h_src = wt_h + (size_t)(j0 + row) * 256 + ch;
  const short* b_l_src = wt_l + (size_t)(j0 + row) * 256 + ch;
  uint4 vah = *(const uint4*)&a_h_src[0];
  uint4 val = *(const uint4*)&a_l_src[0];
  uint4 vbh = *(const uint4*)&b_h_src[0];
  uint4 vbl = *(const uint4*)&b_l_src[0];
  for (int it = 0; it < 8; ++it) {
    __syncthreads();
    *(uint4*)&Ah[row * 40 + ch] = vah;
    *(uint4*)&Al[row * 40 + ch] = val;
    *(uint4*)&Bh[row * 40 + ch] = vbh;
    *(uint4*)&Bl[row * 40 + ch] = vbl;
    __syncthreads();
    int kn = ((it + 1) & 7) * 32;   // wraps to 0 on last iter (harmless reload)
    vah = *(const uint4*)&a_h_src[kn];
    val = *(const uint4*)&a_l_src[kn];
    vbh = *(const uint4*)&b_h_src[kn];
    vbl = *(const uint4*)&b_l_src[kn];
    bf16x8 ah = *(bf16x8*)&Ah[(wid * 16 + lr) * 40 + lq * 8];
    bf16x8 al8 = *(bf16x8*)&Al[(wid * 16 + lr) * 40 + lq * 8];
#pragma unroll
    for (int js = 0; js < 4; ++js) {
      bf16x8 bh = *(bf16x8*)&Bh[(js * 16 + lr) * 40 + lq * 8];
      bf16x8 bl = *(bf16x8*)&Bl[(js * 16 + lr) * 40 + lq * 8];
      acc[js] = __builtin_amdgcn_mfma_f32_16x16x32_bf16(al8, bh, acc[js], 0, 0, 0);
      acc[js] = __builtin_amdgcn_mfma_f32_16x16x32_bf16(ah, bl, acc[js], 0, 0, 0);
      acc[js] = __builtin_amdgcn_mfma_f32_16x16x32_bf16(ah, bh, acc[js], 0, 0, 0);
    }
  }
  __syncthreads();
#pragma unroll
  for (int js = 0; js < 4; ++js)
#pragma unroll
    for (int reg = 0; reg < 4; ++reg)
      ct[wid * 16 + lq * 4 + reg][js * 16 + lr] = acc[js][reg];
  __syncthreads();
  int b = m0 >> 10, n0 = m0 & 1023;
  int three = j0 >> 8;   // blockIdx.y 0-3: Q, 4-7: K, 8-11: V
  const float scale = 0.17677669529663687f;  // 1/sqrt(32), folded into K planes
  if (three == 2) {
    int jl = t >> 2;            // local j 0..63
    int n4 = (t & 3) * 16;      // 16 n-values per thread
    int rem = (j0 & 255) + jl;
    int h = rem >> 5, d = rem & 31;
    short hs[16], ls[16];
#pragma unroll
    for (int u = 0; u < 16; ++u) {
      unsigned hb, lb;
      split_bf(ct[n4 + u][jl], hb, lb);
      hs[u] = (short)hb; ls[u] = (short)lb;
    }
    size_t ob = ((size_t)(b * Hn + h) * Dn + d) * Nn + n0 + n4;
    *(uint4*)&vt_hi[ob] = *(uint4*)&hs[0];
    *(uint4*)&vt_hi[ob + 8] = *(uint4*)&hs[8];
    *(uint4*)&vt_lo[ob] = *(uint4*)&ls[0];
    *(uint4*)&vt_lo[ob + 8] = *(uint4*)&ls[8];
  } else {
    int m_l = t & 63, half = t >> 6;
    int rem = (j0 & 255) + half * 16;
    int h = rem >> 5, ddb = rem & 31;   // 16-aligned
    int n = n0 + m_l;
    float sc = (three == 0) ? 1.0f : scale;
    short* dh = three ? k_hi : q_hi;
    short* dl = three ? k_lo : q_lo;
    short hs[16], ls[16];
#pragma unroll
    for (int u = 0; u < 16; ++u) {
      unsigned hb, lb;
      split_bf(ct[m_l][half * 16 + u] * sc, hb, lb);
      hs[u] = (short)hb; ls[u] = (short)lb;
    }
    size_t base = ((size_t)((b * Hn + h) * Nn + n)) * Dn + ddb;
    *(uint4*)&dh[base] = *(uint4*)&hs[0];
    *(uint4*)&dh[base + 8] = *(uint4*)&hs[8];
    *(uint4*)&dl[base] = *(uint4*)&ls[0];
    *(uint4*)&dl[base + 8] = *(uint4*)&ls[8];
  }
}

// ---------------- K4a: MFMA attention core (1 head/block, m-split x2) --------
// XCD-locality swizzle: the 16 blocks sharing a (b,nt) group (8 heads x 2
// m-halves) re-read the same eg rows + Q panel; mapping them to one XCD
// (blockIdx % 8 == group % 8, per m09 round-robin) makes those re-reads
// L2-local. Balanced: 128 blocks/XCD. Pure index remap, zero numerics.
__global__ __launch_bounds__(256, 4) void k_attn_core(
    const short* __restrict__ q_hi, const short* __restrict__ q_lo,
    const short* __restrict__ k_hi, const short* __restrict__ k_lo,
    const short* __restrict__ vt_hi, const short* __restrict__ vt_lo,
    const float* __restrict__ eg,
    const float* __restrict__ w_expand, const float* __restrict__ b_expand,
    float* __restrict__ o_part, float* __restrict__ l_part) {
  __shared__ short kh[64 * 40];
  __shared__ short kl[64 * 40];
  __shared__ short vth[32 * 72];
  __shared__ short vtl[32 * 72];
  __shared__ unsigned pbuf[4][16 * 68];

  int i = blockIdx.x;
  // i = (G&7) + 8*(M + 16*(G>>3));  G = b*16+nt (64 groups), M = h*2+mh (16)
  int low3 = i & 7, rest = i >> 3;
  int M = rest & 15, Ghi = rest >> 4;
  int G = Ghi * 8 + low3;
  int b = G >> 4, nt = G & 15;
  int h = M >> 1, mh = M & 1;
  int n0 = nt * 64;
  int t = threadIdx.x, wid = t >> 6, l = t & 63;
  int lr = l & 15, lq = l >> 4;

  const float we = w_expand[h], be = b_expand[h];
  size_t bhb = (size_t)(b * Hn + h) * Nn * Dn;
  const short* khg = k_hi + bhb;
  const short* klg = k_lo + bhb;
  const short* vhg = vt_hi + bhb;
  const short* vlg = vt_lo + bhb;

  bf16x8 qhi, qlo;
  {
    size_t qoff = bhb + (size_t)(n0 + wid * 16 + lr) * Dn + lq * 8;
    qhi = *(const bf16x8*)&q_hi[qoff];
    qlo = *(const bf16x8*)&q_lo[qoff];
  }

  // staging coords (fixed per thread)
  int srow = t >> 2, sc = (t & 3) * 8;   // K: row, d-offset
  int sd = t >> 3, scm = (t & 7) * 8;    // V^T: d-row, m-offset
  uint4 rkh, rkl, rvh, rvl;
  {
    int m0 = mh * 512;
    rkh = *(const uint4*)&khg[(size_t)(m0 + srow) * Dn + sc];
    rkl = *(const uint4*)&klg[(size_t)(m0 + srow) * Dn + sc];
    rvh = *(const uint4*)&vhg[(size_t)sd * Nn + m0 + scm];
    rvl = *(const uint4*)&vlg[(size_t)sd * Nn + m0 + scm];
  }

  f32x4 O0 = {0.f, 0.f, 0.f, 0.f}, O1 = {0.f, 0.f, 0.f, 0.f};
  float rowsum[4] = {0.f, 0.f, 0.f, 0.f};
  int nrow = n0 + wid * 16 + lq * 4;

  for (int ms = 0; ms < 8; ++ms) {
    int m0 = mh * 512 + ms * 64;
    float eb[4][4];
#pragma unroll
    for (int reg = 0; reg < 4; ++reg) {
      const float* ep = &eg[(size_t)(b * Nn + nrow + reg) * Nn + m0 + lr];
#pragma unroll
      for (int msub = 0; msub < 4; ++msub) eb[msub][reg] = ep[msub * 16];
    }
    __syncthreads();   // previous tile's readers done
    *(uint4*)&kh[srow * 40 + sc] = rkh;
    *(uint4*)&kl[srow * 40 + sc] = rkl;
    *(uint4*)&vth[sd * 72 + scm] = rvh;
    *(uint4*)&vtl[sd * 72 + scm] = rvl;
    __syncthreads();   // tile ready
    {  // issue next tile's loads now; latency hides under compute below
      int mn0 = mh * 512 + ((ms < 7) ? ms + 1 : ms) * 64;
      rkh = *(const uint4*)&khg[(size_t)(mn0 + srow) * Dn + sc];
      rkl = *(const uint4*)&klg[(size_t)(mn0 + srow) * Dn + sc];
      rvh = *(const uint4*)&vhg[(size_t)sd * Nn + mn0 + scm];
      rvl = *(const uint4*)&vlg[(size_t)sd * Nn + mn0 + scm];
    }

    __builtin_amdgcn_s_setprio(1);
#pragma unroll
    for (int msub = 0; msub < 4; ++msub) {
      int mrow = msub * 16 + lr;
      bf16x8 bh8 = *(bf16x8*)&kh[mrow * 40 + lq * 8];
      bf16x8 bl8 = *(bf16x8*)&kl[mrow * 40 + lq * 8];
      f32x4 sacc = {0.f, 0.f, 0.f, 0.f};
      sacc = __builtin_amdgcn_mfma_f32_16x16x32_bf16(qlo, bh8, sacc, 0, 0, 0);
      sacc = __builtin_amdgcn_mfma_f32_16x16x32_bf16(qhi, bl8, sacc, 0, 0, 0);
      sacc = __builtin_amdgcn_mfma_f32_16x16x32_bf16(qhi, bh8, sacc, 0, 0, 0);
#pragma unroll
      for (int reg = 0; reg < 4; ++reg) {
        float s = sacc[reg] + eb[msub][reg] * we + be;
        float e = __expf(s);
        rowsum[reg] += e;
        pbuf[wid][(lq * 4 + reg) * 68 + msub * 16 + lr] = split_bf_trunc_pack(e);
      }
    }
    __builtin_amdgcn_s_setprio(0);

    __builtin_amdgcn_s_setprio(1);
#pragma unroll
    for (int mw = 0; mw < 2; ++mw) {
      uint4 pa = *(uint4*)&pbuf[wid][lr * 68 + mw * 32 + lq * 8];
      uint4 pb = *(uint4*)&pbuf[wid][lr * 68 + mw * 32 + lq * 8 + 4];
      bf16x8 ahi, alo;
      unpack_u32x8(pa, pb, ahi, alo);
      {
        bf16x8 vh8 = *(bf16x8*)&vth[lr * 72 + mw * 32 + lq * 8];
        bf16x8 vl8 = *(bf16x8*)&vtl[lr * 72 + mw * 32 + lq * 8];
        O0 = __builtin_amdgcn_mfma_f32_16x16x32_bf16(alo, vh8, O0, 0, 0, 0);
        O0 = __builtin_amdgcn_mfma_f32_16x16x32_bf16(ahi, vl8, O0, 0, 0, 0);
        O0 = __builtin_amdgcn_mfma_f32_16x16x32_bf16(ahi, vh8, O0, 0, 0, 0);
      }
      {
        bf16x8 vh8 = *(bf16x8*)&vth[(16 + lr) * 72 + mw * 32 + lq * 8];
        bf16x8 vl8 = *(bf16x8*)&vtl[(16 + lr) * 72 + mw * 32 + lq * 8];
        O1 = __builtin_amdgcn_mfma_f32_16x16x32_bf16(alo, vh8, O1, 0, 0, 0);
        O1 = __builtin_amdgcn_mfma_f32_16x16x32_bf16(ahi, vl8, O1, 0, 0, 0);
        O1 = __builtin_amdgcn_mfma_f32_16x16x32_bf16(ahi, vh8, O1, 0, 0, 0);
      }
    }
    __builtin_amdgcn_s_setprio(0);
  }

#pragma unroll
  for (int reg = 0; reg < 4; ++reg) {
#pragma unroll
    for (int off = 1; off < 16; off <<= 1)
      rowsum[reg] += __shfl_xor(rowsum[reg], off);
  }
  size_t pbase = (size_t)mh * BHND + bhb;
#pragma unroll
  for (int reg = 0; reg < 4; ++reg) {
    int n = nrow + reg;
    o_part[pbase + (size_t)n * Dn + lr] = O0[reg];
    o_part[pbase + (size_t)n * Dn + 16 + lr] = O1[reg];
    if (lr == 0)
      l_part[(size_t)mh * BHN + (size_t)(b * Hn + h) * Nn + n] = rowsum[reg];
  }
}

// ---------------- K4b: edge output + fused softmax partials ------------------
// XCD-locality swizzle: the 16 nt-blocks sharing a (b,mt) group read the same
// K m-tiles (all 8 heads, 64 KB) -> pin each group to one XCD L2.
__global__ __launch_bounds__(256, 4) void k_edge_mfma(
    const short* __restrict__ q_hi, const short* __restrict__ q_lo,
    const short* __restrict__ k_hi, const short* __restrict__ k_lo,
    const float* __restrict__ eg, const float* __restrict__ l_part,
    const float* __restrict__ w_expand, const float* __restrict__ b_expand,
    const float* __restrict__ w_reduce, const float* __restrict__ b_reduce,
    float* __restrict__ edge_out, float* __restrict__ pl_part,
    float* __restrict__ pwe_part) {
  __shared__ short kh[2][64 * 40];
  __shared__ short kl[2][64 * 40];
  int i = blockIdx.x;
  // i = (G&7) + 8*(M + 16*(G>>3));  G = b*16+mt (64 groups), M = nt (16)
  int low3 = i & 7, rest = i >> 3;
  int M = rest & 15, Ghi = rest >> 4;
  int G = Ghi * 8 + low3;
  int b = G >> 4, mt = G & 15;
  int nt = M;
  int n0 = nt * 64, m0 = mt * 64;
  int t = threadIdx.x, wid = t >> 6, l = t & 63;
  int lr = l & 15, lq = l >> 4;
  const float br = b_reduce[0];
  int nrow = n0 + wid * 16 + lq * 4;

  float eacc[4][4], ebias[4][4];
#pragma unroll
  for (int reg = 0; reg < 4; ++reg) {
    const float* ep = &eg[(size_t)(b * Nn + nrow + reg) * Nn + m0 + lr];
#pragma unroll
    for (int msub = 0; msub < 4; ++msub) {
      ebias[msub][reg] = ep[msub * 16];
      eacc[msub][reg] = br;
    }
  }

  int srow = t >> 2, sc = (t & 3) * 8;
  uint4 rkh, rkl;
  {  // tile for h=0
    size_t bhb0 = (size_t)(b * Hn) * Nn * Dn;
    rkh = *(const uint4*)&k_hi[bhb0 + (size_t)(m0 + srow) * Dn + sc];
    rkl = *(const uint4*)&k_lo[bhb0 + (size_t)(m0 + srow) * Dn + sc];
  }
  *(uint4*)&kh[0][srow * 40 + sc] = rkh;
  *(uint4*)&kl[0][srow * 40 + sc] = rkl;
  __syncthreads();

  for (int h = 0; h < Hn; ++h) {
    int pb = h & 1;
    size_t bhb = (size_t)(b * Hn + h) * Nn * Dn;
    float we = w_expand[h], be = b_expand[h], wr = w_reduce[h];
    bf16x8 qhi, qlo;
    {
      size_t qoff = bhb + (size_t)(n0 + wid * 16 + lr) * Dn + lq * 8;
      qhi = *(const bf16x8*)&q_hi[qoff];
      qlo = *(const bf16x8*)&q_lo[qoff];
    }
    float invl[4];
#pragma unroll
    for (int reg = 0; reg < 4; ++reg) {
      size_t idx = (size_t)(b * Hn + h) * Nn + nrow + reg;
      invl[reg] = 1.0f / (l_part[idx] + l_part[BHN + idx]);
    }
    {  // issue next head's K tile loads; written to the other buffer below
      size_t bhn = (size_t)(b * Hn + ((h < 7) ? h + 1 : h)) * Nn * Dn;
      rkh = *(const uint4*)&k_hi[bhn + (size_t)(m0 + srow) * Dn + sc];
      rkl = *(const uint4*)&k_lo[bhn + (size_t)(m0 + srow) * Dn + sc];
    }
    __builtin_amdgcn_s_setprio(1);
#pragma unroll
    for (int msub = 0; msub < 4; ++msub) {
      int mrow = msub * 16 + lr;
      bf16x8 bh8 = *(bf16x8*)&kh[pb][mrow * 40 + lq * 8];
      bf16x8 bl8 = *(bf16x8*)&kl[pb][mrow * 40 + lq * 8];
      f32x4 sacc = {0.f, 0.f, 0.f, 0.f};
      sacc = __builtin_amdgcn_mfma_f32_16x16x32_bf16(qlo, bh8, sacc, 0, 0, 0);
      sacc = __builtin_amdgcn_mfma_f32_16x16x32_bf16(qhi, bl8, sacc, 0, 0, 0);
      sacc = __builtin_amdgcn_mfma_f32_16x16x32_bf16(qhi, bh8, sacc, 0, 0, 0);
#pragma unroll
      for (int reg = 0; reg < 4; ++reg) {
        float s = sacc[reg] + ebias[msub][reg] * we + be;
        float pv = __expf(s) * invl[reg];
        eacc[msub][reg] += wr * (pv + s);
      }
    }
    __builtin_amdgcn_s_setprio(0);
    // write-late: prefetched next-head tile into the other buffer
    *(uint4*)&kh[pb ^ 1][srow * 40 + sc] = rkh;
    *(uint4*)&kl[pb ^ 1][srow * 40 + sc] = rkl;
    __syncthreads();
  }
#pragma unroll
  for (int msub = 0; msub < 4; ++msub)
#pragma unroll
    for (int reg = 0; reg < 4; ++reg)
      edge_out[(size_t)(b * Nn + nrow + reg) * Nn + m0 + msub * 16 + lr] = eacc[msub][reg];

  float pl[4] = {0.f, 0.f, 0.f, 0.f}, pw[4] = {0.f, 0.f, 0.f, 0.f};
#pragma unroll
  for (int msub = 0; msub < 4; ++msub)
#pragma unroll
    for (int reg = 0; reg < 4; ++reg) {
      float e = eacc[msub][reg];
      float x = __expf(e);
      pl[reg] += x;
      pw[reg] += x * e;
    }
#pragma unroll
  for (int reg = 0; reg < 4; ++reg) {
#pragma unroll
    for (int off = 1; off < 16; off <<= 1) {
      pl[reg] += __shfl_xor(pl[reg], off);
      pw[reg] += __shfl_xor(pw[reg], off);
    }
    if (lr == 0) {
      int idx = mt * (Bn * Nn) + b * Nn + nrow + reg;
      pl_part[idx] = pl[reg];
      pwe_part[idx] = pw[reg];
    }
  }
}

// ---------------- K6: proj via split-bf16 MFMA -------------------------------
__global__ __launch_bounds__(256) void k_proj_mfma(
    const float* __restrict__ o_part, const float* __restrict__ l_part,
    const float* __restrict__ pl, const float* __restrict__ pwe,
    const float* __restrict__ wfc, const float* __restrict__ bfc,
    const short* __restrict__ wpt_h, const short* __restrict__ wpt_l,
    const float* __restrict__ bproj, float* __restrict__ out) {
  __shared__ short Ah[64 * 40];
  __shared__ short Al[64 * 40];
  __shared__ short Bh[64 * 40];
  __shared__ short Bl[64 * 40];
  __shared__ float ct[64][65];
  __shared__ float wsm_s[64];
  int m0 = blockIdx.x * 64;
  int j0 = blockIdx.y * 64;
  int t = threadIdx.x, wid = t >> 6, l = t & 63;
  int lr = l & 15, lq = l >> 4;
  if (t < 64) {
    int m = m0 + t;
    float L = 0.f, Wv = 0.f;
#pragma unroll
    for (int mt = 0; mt < 16; ++mt) {
      L += pl[mt * (Bn * Nn) + m];
      Wv += pwe[mt * (Bn * Nn) + m];
    }
    wsm_s[t] = Wv / L;
  }
  __syncthreads();
  f32x4 acc[4] = {};
  int row = t >> 2, kc = (t & 3) * 8;
  int m = m0 + row;
  int bb = m >> 10, n = m & 1023;
  for (int it = 0; it < 8; ++it) {
    int c = it * 32 + kc;
    int h = c >> 5;
    size_t sidx = (size_t)(bb * Hn + h) * Nn + n;
    float inv = 1.0f / (l_part[sidx] + l_part[BHN + sidx]);
    float wsm = wsm_s[row];
    size_t ob = ((size_t)(bb * Hn + h) * Nn + n) * Dn + (c & 31);
    float4 oa0 = *(const float4*)&o_part[ob];
    float4 oa1 = *(const float4*)&o_part[ob + 4];
    float4 oc0 = *(const float4*)&o_part[BHND + ob];
    float4 oc1 = *(const float4*)&o_part[BHND + ob + 4];
    float av[8];
    av[0] = (oa0.x + oc0.x) * inv; av[1] = (oa0.y + oc0.y) * inv;
    av[2] = (oa0.z + oc0.z) * inv; av[3] = (oa0.w + oc0.w) * inv;
    av[4] = (oa1.x + oc1.x) * inv; av[5] = (oa1.y + oc1.y) * inv;
    av[6] = (oa1.z + oc1.z) * inv; av[7] = (oa1.w + oc1.w) * inv;
    short hs[8], ls[8];
#pragma unroll
    for (int j = 0; j < 8; ++j) {
      float a = av[j] + wsm * wfc[c + j] + bfc[c + j];
      unsigned hb, lb; split_bf(a, hb, lb);
      hs[j] = (short)hb; ls[j] = (short)lb;
    }
    __syncthreads();   // previous iter's fragment readers done
    *(uint4*)&Ah[row * 40 + kc] = *(uint4*)&hs[0];
    *(uint4*)&Al[row * 40 + kc] = *(uint4*)&ls[0];
    *(uint4*)&Bh[row * 40 + kc] = *(const uint4*)&wpt_h[(size_t)(j0 + row) * 256 + c];
    *(uint4*)&Bl[row * 40 + kc] = *(const uint4*)&wpt_l[(size_t)(j0 + row) * 256 + c];
    __syncthreads();
    bf16x8 ah = *(bf16x8*)&Ah[(wid * 16 + lr) * 40 + lq * 8];
    bf16x8 al8 = *(bf16x8*)&Al[(wid * 16 + lr) * 40 + lq * 8];
#pragma unroll
    for (int js = 0; js < 4; ++js) {
      bf16x8 bh = *(bf16x8*)&Bh[(js * 16 + lr) * 40 + lq * 8];
      bf16x8 bl = *(bf16x8*)&Bl[(js * 16 + lr) * 40 + lq * 8];
      acc[js] = __builtin_amdgcn_mfma_f32_16x16x32_bf16(al8, bh, acc[js], 0, 0, 0);
      acc[js] = __builtin_amdgcn_mfma_f32_16x16x32_bf16(ah, bl, acc[js], 0, 0, 0);
      acc[js] = __builtin_amdgcn_mfma_f32_16x16x32_bf16(ah, bh, acc[js], 0, 0, 0);
    }
  }
  __syncthreads();
#pragma unroll
  for (int js = 0; js < 4; ++js)
#pragma unroll
    for (int reg = 0; reg < 4; ++reg)
      ct[wid * 16 + lq * 4 + reg][js * 16 + lr] = acc[js][reg] + bproj[j0 + js * 16 + lr];
  __syncthreads();
  int b = m0 >> 10, n0 = m0 & 1023;
  int n4 = t & 15, c0i = t >> 4;
#pragma unroll
  for (int u = 0; u < 4; ++u) {
    int ci = c0i + u * 16;
    float4 val = { ct[(n4 << 2) + 0][ci], ct[(n4 << 2) + 1][ci],
                   ct[(n4 << 2) + 2][ci], ct[(n4 << 2) + 3][ci] };
    *(float4*)&out[(size_t)(b * Cn + j0 + ci) * Nn + n0 + (n4 << 2)] = val;
  }
}

// ---------------- launch ----------------
extern "C" void kernel_launch(void* const* d_in, const int* in_sizes, int n_in,
                              void* d_out, int out_size, void* d_ws, size_t ws_size,
                              hipStream_t stream) {
  (void)in_sizes; (void)n_in; (void)out_size; (void)ws_size;
  const float* node_embeds = (const float*)d_in[0];
  const float* edge_embeds = (const float*)d_in[1];
  const float* da_prior    = (const float*)d_in[2];
  const float* gamma       = (const float*)d_in[3];
  const float* beta        = (const float*)d_in[4];
  const float* w_qkv       = (const float*)d_in[5];
  const float* w_proj      = (const float*)d_in[6];
  const float* b_proj      = (const float*)d_in[7];
  const float* w_expand    = (const float*)d_in[8];
  const float* b_expand    = (const float*)d_in[9];
  const float* w_reduce    = (const float*)d_in[10];
  const float* b_reduce    = (const float*)d_in[11];
  const float* w_fc        = (const float*)d_in[12];
  const float* b_fc        = (const float*)d_in[13];
  float* out_node = (float*)d_out;
  float* out_edge = out_node + (size_t)Bn * Cn * Nn;

  const size_t M = 1048576;  // B*N*C elements
  float* W = (float*)d_ws;
  short* ln_hi  = (short*)(W + M);
  short* ln_lo  = ln_hi + M;
  float* o_part = W;                     // [2][B,H,N,D] overlays ln after death
  short* vt_hi  = (short*)(W + 2 * M);
  short* vt_lo  = vt_hi + M;
  short* q_hi   = (short*)(W + 3 * M);
  short* q_lo   = q_hi + M;
  short* k_hi   = q_hi + 2 * M;
  short* k_lo   = q_hi + 3 * M;
  float* ws_pp    = W + 5 * M;                  // [B*8][C]
  float* l_part   = ws_pp + Bn * 8 * Cn;        // [2][B,H,N]
  float* pl_part  = l_part + 2 * BHN;           // [16][B*N]
  float* pwe_part = pl_part + 16 * Bn * Nn;     // [16][B*N]
  short* wt_hi    = (short*)(pwe_part + 16 * Bn * Nn);
  short* wt_lo    = wt_hi + 768 * 256;
  short* wpt_hi   = wt_lo + 768 * 256;
  short* wpt_lo   = wpt_hi + 256 * 256;

  k_pre<<<dim3(288), dim3(256), 0, stream>>>(w_qkv, w_proj, da_prior,
                                             wt_hi, wt_lo, wpt_hi, wpt_lo, ws_pp);
  k_prep_ln<<<dim3(Bn * Nn), dim3(256), 0, stream>>>(node_embeds, edge_embeds, ws_pp,
                                                     gamma, beta, ln_hi, ln_lo);
  k_qkv_mfma<<<dim3(64, 12), dim3(256), 0, stream>>>(ln_hi, ln_lo, wt_hi, wt_lo,
                                                     q_hi, q_lo, k_hi, k_lo,
                                                     vt_hi, vt_lo);
  k_attn_core<<<dim3(Bn * Hn * 16 * 2), dim3(256), 0, stream>>>(
      q_hi, q_lo, k_hi, k_lo, vt_hi, vt_lo, edge_embeds, w_expand, b_expand,
      o_part, l_part);
  k_edge_mfma<<<dim3(Bn * 16 * 16), dim3(256), 0, stream>>>(
      q_hi, q_lo, k_hi, k_lo, edge_embeds, l_part, w_expand, b_expand,
      w_reduce, b_reduce, out_edge, pl_part, pwe_part);
  k_proj_mfma<<<dim3(64, 4), dim3(256), 0, stream>>>(o_part, l_part, pl_part,
                                                     pwe_part, w_fc, b_fc,
                                                     wpt_hi, wpt_lo, b_proj,
                                                     out_node);
}

// Round 10
// 173.613 us; speedup vs baseline: 1.0167x; 1.0167x over previous
//
#include <hip/hip_runtime.h>
#include <math.h>

#define Bn 4
#define Cn 256
#define Nn 1024
#define Hn 8
#define Dn 32
#define BHND (Bn * Hn * Nn * Dn)   // 1048576
#define BHN  (Bn * Hn * Nn)        // 32768

typedef short bf16x8 __attribute__((ext_vector_type(8)));
typedef float f32x4 __attribute__((ext_vector_type(4)));

__device__ inline unsigned f2bf_rn_bits(float x) {
  union { float f; unsigned u; } v; v.f = x;
  return (v.u + 0x7FFFu + ((v.u >> 16) & 1u)) >> 16;
}
__device__ inline float bfbits2f(unsigned b) {
  union { unsigned u; float f; } v; v.u = b << 16; return v.f;
}
__device__ inline void split_bf(float x, unsigned& hi, unsigned& lo) {
  hi = f2bf_rn_bits(x);
  lo = f2bf_rn_bits(x - bfbits2f(hi));
}
// truncation split (cheaper; lo absorbs hi error, ~2^-16 rel)
__device__ inline unsigned split_bf_trunc_pack(float x) {
  union { float f; unsigned u; } v; v.f = x;
  unsigned hi = v.u >> 16;
  union { unsigned u; float f; } hv; hv.u = hi << 16;
  union { float f; unsigned u; } r; r.f = x - hv.f;
  return hi | (r.u & 0xffff0000u);
}
__device__ inline void unpack_u32x8(const uint4& a, const uint4& b, bf16x8& hi, bf16x8& lo) {
  int4 h4, l4;
  h4.x = (int)((a.x & 0xffffu) | (a.y << 16));  l4.x = (int)((a.x >> 16) | (a.y & 0xffff0000u));
  h4.y = (int)((a.z & 0xffffu) | (a.w << 16));  l4.y = (int)((a.z >> 16) | (a.w & 0xffff0000u));
  h4.z = (int)((b.x & 0xffffu) | (b.y << 16));  l4.z = (int)((b.x >> 16) | (b.y & 0xffff0000u));
  h4.w = (int)((b.z & 0xffffu) | (b.w << 16));  l4.w = (int)((b.z >> 16) | (b.w & 0xffff0000u));
  hi = *(bf16x8*)&h4; lo = *(bf16x8*)&l4;
}

// ---------------- K0: fused root dispatch ----------------
// blocks [0,32):    prior partial sums (8 chunks of 128 n per b)
// blocks [32,224):  transpose+split w_qkv [C,3C] -> wt hi/lo [3C,C]
// blocks [224,288): transpose+split w_proj [C,C] -> wpt hi/lo [C,C]
__global__ __launch_bounds__(256) void k_pre(const float* __restrict__ w,
                                             const float* __restrict__ wp,
                                             const float* __restrict__ dap,
                                             short* __restrict__ wt_h,
                                             short* __restrict__ wt_l,
                                             short* __restrict__ wpt_h,
                                             short* __restrict__ wpt_l,
                                             float* __restrict__ pp) {
  __shared__ float tile[32][33];
  int bi = blockIdx.x;
  if (bi < 32) {
    int b = bi >> 3, ch = bi & 7;
    int c = threadIdx.x;
    float s = 0.f;
    int n0 = ch * 128;
    for (int n = n0; n < n0 + 128; ++n) s += dap[(size_t)(b * Nn + n) * Cn + c];
    pp[(size_t)bi * Cn + c] = s;
  } else if (bi < 224) {
    int wi = bi - 32;
    int j0 = (wi >> 3) << 5;   // 0..736
    int k0 = (wi & 7) << 5;    // 0..224
    int tx = threadIdx.x & 31, ty = threadIdx.x >> 5;
#pragma unroll
    for (int i = 0; i < 4; ++i)
      tile[ty + i * 8][tx] = w[(size_t)(k0 + ty + i * 8) * 768 + j0 + tx];
    __syncthreads();
#pragma unroll
    for (int i = 0; i < 4; ++i) {
      float v = tile[tx][ty + i * 8];
      unsigned hb, lb; split_bf(v, hb, lb);
      wt_h[(size_t)(j0 + ty + i * 8) * 256 + k0 + tx] = (short)hb;
      wt_l[(size_t)(j0 + ty + i * 8) * 256 + k0 + tx] = (short)lb;
    }
  } else {
    int wi = bi - 224;
    int j0 = (wi >> 3) << 5;   // 0..224
    int k0 = (wi & 7) << 5;    // 0..224
    int tx = threadIdx.x & 31, ty = threadIdx.x >> 5;
#pragma unroll
    for (int i = 0; i < 4; ++i)
      tile[ty + i * 8][tx] = wp[(size_t)(k0 + ty + i * 8) * 256 + j0 + tx];
    __syncthreads();
#pragma unroll
    for (int i = 0; i < 4; ++i) {
      float v = tile[tx][ty + i * 8];
      unsigned hb, lb; split_bf(v, hb, lb);
      wpt_h[(size_t)(j0 + ty + i * 8) * 256 + k0 + tx] = (short)hb;
      wpt_l[(size_t)(j0 + ty + i * 8) * 256 + k0 + tx] = (short)lb;
    }
  }
}

// ---------------- K2: prep (diag*x*prior + x) + LayerNorm -> bf16 hi/lo -------
__global__ __launch_bounds__(256) void k_prep_ln(const float* __restrict__ ne,
                                                 const float* __restrict__ eg,
                                                 const float* __restrict__ pp,
                                                 const float* __restrict__ gamma,
                                                 const float* __restrict__ beta,
                                                 short* __restrict__ ln_h,
                                                 short* __restrict__ ln_l) {
  int bn = blockIdx.x;
  int b = bn >> 10, n = bn & 1023;
  int c = threadIdx.x;
  float x = ne[(size_t)(b * Cn + c) * Nn + n];
  float pr = 0.f;
#pragma unroll
  for (int ch = 0; ch < 8; ++ch) pr += pp[(size_t)(b * 8 + ch) * Cn + c];
  float dg = eg[(size_t)(b * Nn + n) * Nn + n];
  float x2 = x * (1.f + dg * pr);
  float s = x2, qq = x2 * x2;
#pragma unroll
  for (int off = 32; off >= 1; off >>= 1) {
    s += __shfl_xor(s, off);
    qq += __shfl_xor(qq, off);
  }
  __shared__ float ss[4], sq[4];
  if ((c & 63) == 0) { ss[c >> 6] = s; sq[c >> 6] = qq; }
  __syncthreads();
  s = ss[0] + ss[1] + ss[2] + ss[3];
  qq = sq[0] + sq[1] + sq[2] + sq[3];
  float mu = s * (1.f / 256.f);
  float var = qq * (1.f / 256.f) - mu * mu;
  float r = rsqrtf(var + 1e-5f);
  float v = (x2 - mu) * r * gamma[c] + beta[c];
  unsigned hb, lb; split_bf(v, hb, lb);
  ln_h[(size_t)bn * Cn + c] = (short)hb;
  ln_l[(size_t)bn * Cn + c] = (short)lb;
}

// ---------------- K3: QKV GEMM via split-bf16 MFMA, LDS-staged tiles ----------
__global__ __launch_bounds__(256) void k_qkv_mfma(
    const short* __restrict__ ln_h, const short* __restrict__ ln_l,
    const short* __restrict__ wt_h, const short* __restrict__ wt_l,
    short* __restrict__ q_hi, short* __restrict__ q_lo,
    short* __restrict__ k_hi, short* __restrict__ k_lo,
    short* __restrict__ vt_hi, short* __restrict__ vt_lo) {
  __shared__ short Ah[64 * 40];
  __shared__ short Al[64 * 40];
  __shared__ short Bh[64 * 40];
  __shared__ short Bl[64 * 40];
  __shared__ float ct[64][65];
  int m0 = blockIdx.x * 64;
  int j0 = blockIdx.y * 64;
  int t = threadIdx.x, wid = t >> 6, l = t & 63;
  int lr = l & 15, lq = l >> 4;
  f32x4 acc[4] = {};
  int row = t >> 2, ch = (t & 3) * 8;
  const short* a_h_src = ln_h + (size_t)(m0 + row) * 256 + ch;
  const short* a_l_src = ln_l + (size_t)(m0 + row) * 256 + ch;
  const short* b_h_src = wt_h + (size_t)(j0 + row) * 256 + ch;
  const short* b_l_src = wt_l + (size_t)(j0 + row) * 256 + ch;
  uint4 vah = *(const uint4*)&a_h_src[0];
  uint4 val = *(const uint4*)&a_l_src[0];
  uint4 vbh = *(const uint4*)&b_h_src[0];
  uint4 vbl = *(const uint4*)&b_l_src[0];
  for (int it = 0; it < 8; ++it) {
    __syncthreads();
    *(uint4*)&Ah[row * 40 + ch] = vah;
    *(uint4*)&Al[row * 40 + ch] = val;
    *(uint4*)&Bh[row * 40 + ch] = vbh;
    *(uint4*)&Bl[row * 40 + ch] = vbl;
    __syncthreads();
    int kn = ((it + 1) & 7) * 32;   // wraps to 0 on last iter (harmless reload)
    vah = *(const uint4*)&a_h_src[kn];
    val = *(const uint4*)&a_l_src[kn];
    vbh = *(const uint4*)&b_h_src[kn];
    vbl = *(const uint4*)&b_l_src[kn];
    bf16x8 ah = *(bf16x8*)&Ah[(wid * 16 + lr) * 40 + lq * 8];
    bf16x8 al8 = *(bf16x8*)&Al[(wid * 16 + lr) * 40 + lq * 8];
#pragma unroll
    for (int js = 0; js < 4; ++js) {
      bf16x8 bh = *(bf16x8*)&Bh[(js * 16 + lr) * 40 + lq * 8];
      bf16x8 bl = *(bf16x8*)&Bl[(js * 16 + lr) * 40 + lq * 8];
      acc[js] = __builtin_amdgcn_mfma_f32_16x16x32_bf16(al8, bh, acc[js], 0, 0, 0);
      acc[js] = __builtin_amdgcn_mfma_f32_16x16x32_bf16(ah, bl, acc[js], 0, 0, 0);
      acc[js] = __builtin_amdgcn_mfma_f32_16x16x32_bf16(ah, bh, acc[js], 0, 0, 0);
    }
  }
  __syncthreads();
#pragma unroll
  for (int js = 0; js < 4; ++js)
#pragma unroll
    for (int reg = 0; reg < 4; ++reg)
      ct[wid * 16 + lq * 4 + reg][js * 16 + lr] = acc[js][reg];
  __syncthreads();
  int b = m0 >> 10, n0 = m0 & 1023;
  int three = j0 >> 8;   // blockIdx.y 0-3: Q, 4-7: K, 8-11: V
  const float scale = 0.17677669529663687f;  // 1/sqrt(32), folded into K planes
  if (three == 2) {
    int jl = t >> 2;            // local j 0..63
    int n4 = (t & 3) * 16;      // 16 n-values per thread
    int rem = (j0 & 255) + jl;
    int h = rem >> 5, d = rem & 31;
    short hs[16], ls[16];
#pragma unroll
    for (int u = 0; u < 16; ++u) {
      unsigned hb, lb;
      split_bf(ct[n4 + u][jl], hb, lb);
      hs[u] = (short)hb; ls[u] = (short)lb;
    }
    size_t ob = ((size_t)(b * Hn + h) * Dn + d) * Nn + n0 + n4;
    *(uint4*)&vt_hi[ob] = *(uint4*)&hs[0];
    *(uint4*)&vt_hi[ob + 8] = *(uint4*)&hs[8];
    *(uint4*)&vt_lo[ob] = *(uint4*)&ls[0];
    *(uint4*)&vt_lo[ob + 8] = *(uint4*)&ls[8];
  } else {
    int m_l = t & 63, half = t >> 6;
    int rem = (j0 & 255) + half * 16;
    int h = rem >> 5, ddb = rem & 31;   // 16-aligned
    int n = n0 + m_l;
    float sc = (three == 0) ? 1.0f : scale;
    short* dh = three ? k_hi : q_hi;
    short* dl = three ? k_lo : q_lo;
    short hs[16], ls[16];
#pragma unroll
    for (int u = 0; u < 16; ++u) {
      unsigned hb, lb;
      split_bf(ct[m_l][half * 16 + u] * sc, hb, lb);
      hs[u] = (short)hb; ls[u] = (short)lb;
    }
    size_t base = ((size_t)((b * Hn + h) * Nn + n)) * Dn + ddb;
    *(uint4*)&dh[base] = *(uint4*)&hs[0];
    *(uint4*)&dh[base + 8] = *(uint4*)&hs[8];
    *(uint4*)&dl[base] = *(uint4*)&ls[0];
    *(uint4*)&dl[base + 8] = *(uint4*)&ls[8];
  }
}

// ---------------- K4a: MFMA attention core (1 head/block, m-split x2) --------
__global__ __launch_bounds__(256, 4) void k_attn_core(
    const short* __restrict__ q_hi, const short* __restrict__ q_lo,
    const short* __restrict__ k_hi, const short* __restrict__ k_lo,
    const short* __restrict__ vt_hi, const short* __restrict__ vt_lo,
    const float* __restrict__ eg,
    const float* __restrict__ w_expand, const float* __restrict__ b_expand,
    float* __restrict__ o_part, float* __restrict__ l_part) {
  __shared__ short kh[64 * 40];
  __shared__ short kl[64 * 40];
  __shared__ short vth[32 * 72];
  __shared__ short vtl[32 * 72];
  __shared__ unsigned pbuf[4][16 * 68];

  int blk = blockIdx.x;
  int mh = blk & 1;
  int nt = (blk >> 1) & 15;
  int h = (blk >> 5) & 7;
  int b = blk >> 8;
  int n0 = nt * 64;
  int t = threadIdx.x, wid = t >> 6, l = t & 63;
  int lr = l & 15, lq = l >> 4;

  const float we = w_expand[h], be = b_expand[h];
  size_t bhb = (size_t)(b * Hn + h) * Nn * Dn;
  const short* khg = k_hi + bhb;
  const short* klg = k_lo + bhb;
  const short* vhg = vt_hi + bhb;
  const short* vlg = vt_lo + bhb;

  bf16x8 qhi, qlo;
  {
    size_t qoff = bhb + (size_t)(n0 + wid * 16 + lr) * Dn + lq * 8;
    qhi = *(const bf16x8*)&q_hi[qoff];
    qlo = *(const bf16x8*)&q_lo[qoff];
  }

  // staging coords (fixed per thread)
  int srow = t >> 2, sc = (t & 3) * 8;   // K: row, d-offset
  int sd = t >> 3, scm = (t & 7) * 8;    // V^T: d-row, m-offset
  uint4 rkh, rkl, rvh, rvl;
  {
    int m0 = mh * 512;
    rkh = *(const uint4*)&khg[(size_t)(m0 + srow) * Dn + sc];
    rkl = *(const uint4*)&klg[(size_t)(m0 + srow) * Dn + sc];
    rvh = *(const uint4*)&vhg[(size_t)sd * Nn + m0 + scm];
    rvl = *(const uint4*)&vlg[(size_t)sd * Nn + m0 + scm];
  }

  f32x4 O0 = {0.f, 0.f, 0.f, 0.f}, O1 = {0.f, 0.f, 0.f, 0.f};
  float rowsum[4] = {0.f, 0.f, 0.f, 0.f};
  int nrow = n0 + wid * 16 + lq * 4;

  for (int ms = 0; ms < 8; ++ms) {
    int m0 = mh * 512 + ms * 64;
    float eb[4][4];
#pragma unroll
    for (int reg = 0; reg < 4; ++reg) {
      const float* ep = &eg[(size_t)(b * Nn + nrow + reg) * Nn + m0 + lr];
#pragma unroll
      for (int msub = 0; msub < 4; ++msub) eb[msub][reg] = ep[msub * 16];
    }
    __syncthreads();   // previous tile's readers done
    *(uint4*)&kh[srow * 40 + sc] = rkh;
    *(uint4*)&kl[srow * 40 + sc] = rkl;
    *(uint4*)&vth[sd * 72 + scm] = rvh;
    *(uint4*)&vtl[sd * 72 + scm] = rvl;
    __syncthreads();   // tile ready
    {  // issue next tile's loads now; latency hides under compute below
      int mn0 = mh * 512 + ((ms < 7) ? ms + 1 : ms) * 64;
      rkh = *(const uint4*)&khg[(size_t)(mn0 + srow) * Dn + sc];
      rkl = *(const uint4*)&klg[(size_t)(mn0 + srow) * Dn + sc];
      rvh = *(const uint4*)&vhg[(size_t)sd * Nn + mn0 + scm];
      rvl = *(const uint4*)&vlg[(size_t)sd * Nn + mn0 + scm];
    }

    __builtin_amdgcn_s_setprio(1);
#pragma unroll
    for (int msub = 0; msub < 4; ++msub) {
      int mrow = msub * 16 + lr;
      bf16x8 bh8 = *(bf16x8*)&kh[mrow * 40 + lq * 8];
      bf16x8 bl8 = *(bf16x8*)&kl[mrow * 40 + lq * 8];
      f32x4 sacc = {0.f, 0.f, 0.f, 0.f};
      sacc = __builtin_amdgcn_mfma_f32_16x16x32_bf16(qlo, bh8, sacc, 0, 0, 0);
      sacc = __builtin_amdgcn_mfma_f32_16x16x32_bf16(qhi, bl8, sacc, 0, 0, 0);
      sacc = __builtin_amdgcn_mfma_f32_16x16x32_bf16(qhi, bh8, sacc, 0, 0, 0);
#pragma unroll
      for (int reg = 0; reg < 4; ++reg) {
        float s = sacc[reg] + eb[msub][reg] * we + be;
        float e = __expf(s);
        rowsum[reg] += e;
        pbuf[wid][(lq * 4 + reg) * 68 + msub * 16 + lr] = split_bf_trunc_pack(e);
      }
    }
    __builtin_amdgcn_s_setprio(0);

    __builtin_amdgcn_s_setprio(1);
#pragma unroll
    for (int mw = 0; mw < 2; ++mw) {
      uint4 pa = *(uint4*)&pbuf[wid][lr * 68 + mw * 32 + lq * 8];
      uint4 pb = *(uint4*)&pbuf[wid][lr * 68 + mw * 32 + lq * 8 + 4];
      bf16x8 ahi, alo;
      unpack_u32x8(pa, pb, ahi, alo);
      {
        bf16x8 vh8 = *(bf16x8*)&vth[lr * 72 + mw * 32 + lq * 8];
        bf16x8 vl8 = *(bf16x8*)&vtl[lr * 72 + mw * 32 + lq * 8];
        O0 = __builtin_amdgcn_mfma_f32_16x16x32_bf16(alo, vh8, O0, 0, 0, 0);
        O0 = __builtin_amdgcn_mfma_f32_16x16x32_bf16(ahi, vl8, O0, 0, 0, 0);
        O0 = __builtin_amdgcn_mfma_f32_16x16x32_bf16(ahi, vh8, O0, 0, 0, 0);
      }
      {
        bf16x8 vh8 = *(bf16x8*)&vth[(16 + lr) * 72 + mw * 32 + lq * 8];
        bf16x8 vl8 = *(bf16x8*)&vtl[(16 + lr) * 72 + mw * 32 + lq * 8];
        O1 = __builtin_amdgcn_mfma_f32_16x16x32_bf16(alo, vh8, O1, 0, 0, 0);
        O1 = __builtin_amdgcn_mfma_f32_16x16x32_bf16(ahi, vl8, O1, 0, 0, 0);
        O1 = __builtin_amdgcn_mfma_f32_16x16x32_bf16(ahi, vh8, O1, 0, 0, 0);
      }
    }
    __builtin_amdgcn_s_setprio(0);
  }

#pragma unroll
  for (int reg = 0; reg < 4; ++reg) {
#pragma unroll
    for (int off = 1; off < 16; off <<= 1)
      rowsum[reg] += __shfl_xor(rowsum[reg], off);
  }
  size_t pbase = (size_t)mh * BHND + bhb;
#pragma unroll
  for (int reg = 0; reg < 4; ++reg) {
    int n = nrow + reg;
    o_part[pbase + (size_t)n * Dn + lr] = O0[reg];
    o_part[pbase + (size_t)n * Dn + 16 + lr] = O1[reg];
    if (lr == 0)
      l_part[(size_t)mh * BHN + (size_t)(b * Hn + h) * Nn + n] = rowsum[reg];
  }
}

// ---------------- K4b: edge output + fused softmax partials ------------------
// Round-4 proven shape + double-buffered K LDS (write-late).
__global__ __launch_bounds__(256, 4) void k_edge_mfma(
    const short* __restrict__ q_hi, const short* __restrict__ q_lo,
    const short* __restrict__ k_hi, const short* __restrict__ k_lo,
    const float* __restrict__ eg, const float* __restrict__ l_part,
    const float* __restrict__ w_expand, const float* __restrict__ b_expand,
    const float* __restrict__ w_reduce, const float* __restrict__ b_reduce,
    float* __restrict__ edge_out, float* __restrict__ pl_part,
    float* __restrict__ pwe_part) {
  __shared__ short kh[2][64 * 40];
  __shared__ short kl[2][64 * 40];
  int blk = blockIdx.x;
  int mt = blk & 15;
  int nt = (blk >> 4) & 15;
  int b = blk >> 8;
  int n0 = nt * 64, m0 = mt * 64;
  int t = threadIdx.x, wid = t >> 6, l = t & 63;
  int lr = l & 15, lq = l >> 4;
  const float br = b_reduce[0];
  int nrow = n0 + wid * 16 + lq * 4;

  float eacc[4][4], ebias[4][4];
#pragma unroll
  for (int reg = 0; reg < 4; ++reg) {
    const float* ep = &eg[(size_t)(b * Nn + nrow + reg) * Nn + m0 + lr];
#pragma unroll
    for (int msub = 0; msub < 4; ++msub) {
      ebias[msub][reg] = ep[msub * 16];
      eacc[msub][reg] = br;
    }
  }

  int srow = t >> 2, sc = (t & 3) * 8;
  uint4 rkh, rkl;
  {  // tile for h=0
    size_t bhb0 = (size_t)(b * Hn) * Nn * Dn;
    rkh = *(const uint4*)&k_hi[bhb0 + (size_t)(m0 + srow) * Dn + sc];
    rkl = *(const uint4*)&k_lo[bhb0 + (size_t)(m0 + srow) * Dn + sc];
  }
  *(uint4*)&kh[0][srow * 40 + sc] = rkh;
  *(uint4*)&kl[0][srow * 40 + sc] = rkl;
  __syncthreads();

  for (int h = 0; h < Hn; ++h) {
    int pb = h & 1;
    size_t bhb = (size_t)(b * Hn + h) * Nn * Dn;
    float we = w_expand[h], be = b_expand[h], wr = w_reduce[h];
    bf16x8 qhi, qlo;
    {
      size_t qoff = bhb + (size_t)(n0 + wid * 16 + lr) * Dn + lq * 8;
      qhi = *(const bf16x8*)&q_hi[qoff];
      qlo = *(const bf16x8*)&q_lo[qoff];
    }
    float invl[4];
#pragma unroll
    for (int reg = 0; reg < 4; ++reg) {
      size_t idx = (size_t)(b * Hn + h) * Nn + nrow + reg;
      invl[reg] = 1.0f / (l_part[idx] + l_part[BHN + idx]);
    }
    {  // issue next head's K tile loads; written to the other buffer below
      size_t bhn = (size_t)(b * Hn + ((h < 7) ? h + 1 : h)) * Nn * Dn;
      rkh = *(const uint4*)&k_hi[bhn + (size_t)(m0 + srow) * Dn + sc];
      rkl = *(const uint4*)&k_lo[bhn + (size_t)(m0 + srow) * Dn + sc];
    }
    __builtin_amdgcn_s_setprio(1);
#pragma unroll
    for (int msub = 0; msub < 4; ++msub) {
      int mrow = msub * 16 + lr;
      bf16x8 bh8 = *(bf16x8*)&kh[pb][mrow * 40 + lq * 8];
      bf16x8 bl8 = *(bf16x8*)&kl[pb][mrow * 40 + lq * 8];
      f32x4 sacc = {0.f, 0.f, 0.f, 0.f};
      sacc = __builtin_amdgcn_mfma_f32_16x16x32_bf16(qlo, bh8, sacc, 0, 0, 0);
      sacc = __builtin_amdgcn_mfma_f32_16x16x32_bf16(qhi, bl8, sacc, 0, 0, 0);
      sacc = __builtin_amdgcn_mfma_f32_16x16x32_bf16(qhi, bh8, sacc, 0, 0, 0);
#pragma unroll
      for (int reg = 0; reg < 4; ++reg) {
        float s = sacc[reg] + ebias[msub][reg] * we + be;
        float pv = __expf(s) * invl[reg];
        eacc[msub][reg] += wr * (pv + s);
      }
    }
    __builtin_amdgcn_s_setprio(0);
    // write-late: prefetched next-head tile into the other buffer
    *(uint4*)&kh[pb ^ 1][srow * 40 + sc] = rkh;
    *(uint4*)&kl[pb ^ 1][srow * 40 + sc] = rkl;
    __syncthreads();
  }
#pragma unroll
  for (int msub = 0; msub < 4; ++msub)
#pragma unroll
    for (int reg = 0; reg < 4; ++reg)
      edge_out[(size_t)(b * Nn + nrow + reg) * Nn + m0 + msub * 16 + lr] = eacc[msub][reg];

  float pl[4] = {0.f, 0.f, 0.f, 0.f}, pw[4] = {0.f, 0.f, 0.f, 0.f};
#pragma unroll
  for (int msub = 0; msub < 4; ++msub)
#pragma unroll
    for (int reg = 0; reg < 4; ++reg) {
      float e = eacc[msub][reg];
      float x = __expf(e);
      pl[reg] += x;
      pw[reg] += x * e;
    }
#pragma unroll
  for (int reg = 0; reg < 4; ++reg) {
#pragma unroll
    for (int off = 1; off < 16; off <<= 1) {
      pl[reg] += __shfl_xor(pl[reg], off);
      pw[reg] += __shfl_xor(pw[reg], off);
    }
    if (lr == 0) {
      int idx = mt * (Bn * Nn) + b * Nn + nrow + reg;
      pl_part[idx] = pl[reg];
      pwe_part[idx] = pw[reg];
    }
  }
}

// ---------------- K6: proj via split-bf16 MFMA -------------------------------
__global__ __launch_bounds__(256) void k_proj_mfma(
    const float* __restrict__ o_part, const float* __restrict__ l_part,
    const float* __restrict__ pl, const float* __restrict__ pwe,
    const float* __restrict__ wfc, const float* __restrict__ bfc,
    const short* __restrict__ wpt_h, const short* __restrict__ wpt_l,
    const float* __restrict__ bproj, float* __restrict__ out) {
  __shared__ short Ah[64 * 40];
  __shared__ short Al[64 * 40];
  __shared__ short Bh[64 * 40];
  __shared__ short Bl[64 * 40];
  __shared__ float ct[64][65];
  __shared__ float wsm_s[64];
  int m0 = blockIdx.x * 64;
  int j0 = blockIdx.y * 64;
  int t = threadIdx.x, wid = t >> 6, l = t & 63;
  int lr = l & 15, lq = l >> 4;
  if (t < 64) {
    int m = m0 + t;
    float L = 0.f, Wv = 0.f;
#pragma unroll
    for (int mt = 0; mt < 16; ++mt) {
      L += pl[mt * (Bn * Nn) + m];
      Wv += pwe[mt * (Bn * Nn) + m];
    }
    wsm_s[t] = Wv / L;
  }
  __syncthreads();
  f32x4 acc[4] = {};
  int row = t >> 2, kc = (t & 3) * 8;
  int m = m0 + row;
  int bb = m >> 10, n = m & 1023;
  for (int it = 0; it < 8; ++it) {
    int c = it * 32 + kc;
    int h = c >> 5;
    size_t sidx = (size_t)(bb * Hn + h) * Nn + n;
    float inv = 1.0f / (l_part[sidx] + l_part[BHN + sidx]);
    float wsm = wsm_s[row];
    size_t ob = ((size_t)(bb * Hn + h) * Nn + n) * Dn + (c & 31);
    float4 oa0 = *(const float4*)&o_part[ob];
    float4 oa1 = *(const float4*)&o_part[ob + 4];
    float4 oc0 = *(const float4*)&o_part[BHND + ob];
    float4 oc1 = *(const float4*)&o_part[BHND + ob + 4];
    float av[8];
    av[0] = (oa0.x + oc0.x) * inv; av[1] = (oa0.y + oc0.y) * inv;
    av[2] = (oa0.z + oc0.z) * inv; av[3] = (oa0.w + oc0.w) * inv;
    av[4] = (oa1.x + oc1.x) * inv; av[5] = (oa1.y + oc1.y) * inv;
    av[6] = (oa1.z + oc1.z) * inv; av[7] = (oa1.w + oc1.w) * inv;
    short hs[8], ls[8];
#pragma unroll
    for (int j = 0; j < 8; ++j) {
      float a = av[j] + wsm * wfc[c + j] + bfc[c + j];
      unsigned hb, lb; split_bf(a, hb, lb);
      hs[j] = (short)hb; ls[j] = (short)lb;
    }
    __syncthreads();   // previous iter's fragment readers done
    *(uint4*)&Ah[row * 40 + kc] = *(uint4*)&hs[0];
    *(uint4*)&Al[row * 40 + kc] = *(uint4*)&ls[0];
    *(uint4*)&Bh[row * 40 + kc] = *(const uint4*)&wpt_h[(size_t)(j0 + row) * 256 + c];
    *(uint4*)&Bl[row * 40 + kc] = *(const uint4*)&wpt_l[(size_t)(j0 + row) * 256 + c];
    __syncthreads();
    bf16x8 ah = *(bf16x8*)&Ah[(wid * 16 + lr) * 40 + lq * 8];
    bf16x8 al8 = *(bf16x8*)&Al[(wid * 16 + lr) * 40 + lq * 8];
#pragma unroll
    for (int js = 0; js < 4; ++js) {
      bf16x8 bh = *(bf16x8*)&Bh[(js * 16 + lr) * 40 + lq * 8];
      bf16x8 bl = *(bf16x8*)&Bl[(js * 16 + lr) * 40 + lq * 8];
      acc[js] = __builtin_amdgcn_mfma_f32_16x16x32_bf16(al8, bh, acc[js], 0, 0, 0);
      acc[js] = __builtin_amdgcn_mfma_f32_16x16x32_bf16(ah, bl, acc[js], 0, 0, 0);
      acc[js] = __builtin_amdgcn_mfma_f32_16x16x32_bf16(ah, bh, acc[js], 0, 0, 0);
    }
  }
  __syncthreads();
#pragma unroll
  for (int js = 0; js < 4; ++js)
#pragma unroll
    for (int reg = 0; reg < 4; ++reg)
      ct[wid * 16 + lq * 4 + reg][js * 16 + lr] = acc[js][reg] + bproj[j0 + js * 16 + lr];
  __syncthreads();
  int b = m0 >> 10, n0 = m0 & 1023;
  int n4 = t & 15, c0i = t >> 4;
#pragma unroll
  for (int u = 0; u < 4; ++u) {
    int ci = c0i + u * 16;
    float4 val = { ct[(n4 << 2) + 0][ci], ct[(n4 << 2) + 1][ci],
                   ct[(n4 << 2) + 2][ci], ct[(n4 << 2) + 3][ci] };
    *(float4*)&out[(size_t)(b * Cn + j0 + ci) * Nn + n0 + (n4 << 2)] = val;
  }
}

// ---------------- launch ----------------
extern "C" void kernel_launch(void* const* d_in, const int* in_sizes, int n_in,
                              void* d_out, int out_size, void* d_ws, size_t ws_size,
                              hipStream_t stream) {
  (void)in_sizes; (void)n_in; (void)out_size; (void)ws_size;
  const float* node_embeds = (const float*)d_in[0];
  const float* edge_embeds = (const float*)d_in[1];
  const float* da_prior    = (const float*)d_in[2];
  const float* gamma       = (const float*)d_in[3];
  const float* beta        = (const float*)d_in[4];
  const float* w_qkv       = (const float*)d_in[5];
  const float* w_proj      = (const float*)d_in[6];
  const float* b_proj      = (const float*)d_in[7];
  const float* w_expand    = (const float*)d_in[8];
  const float* b_expand    = (const float*)d_in[9];
  const float* w_reduce    = (const float*)d_in[10];
  const float* b_reduce    = (const float*)d_in[11];
  const float* w_fc        = (const float*)d_in[12];
  const float* b_fc        = (const float*)d_in[13];
  float* out_node = (float*)d_out;
  float* out_edge = out_node + (size_t)Bn * Cn * Nn;

  const size_t M = 1048576;  // B*N*C elements
  float* W = (float*)d_ws;
  short* ln_hi  = (short*)(W + M);
  short* ln_lo  = ln_hi + M;
  float* o_part = W;                     // [2][B,H,N,D] overlays ln after death
  short* vt_hi  = (short*)(W + 2 * M);
  short* vt_lo  = vt_hi + M;
  short* q_hi   = (short*)(W + 3 * M);
  short* q_lo   = q_hi + M;
  short* k_hi   = q_hi + 2 * M;
  short* k_lo   = q_hi + 3 * M;
  float* ws_pp    = W + 5 * M;                  // [B*8][C]
  float* l_part   = ws_pp + Bn * 8 * Cn;        // [2][B,H,N]
  float* pl_part  = l_part + 2 * BHN;           // [16][B*N]
  float* pwe_part = pl_part + 16 * Bn * Nn;     // [16][B*N]
  short* wt_hi    = (short*)(pwe_part + 16 * Bn * Nn);
  short* wt_lo    = wt_hi + 768 * 256;
  short* wpt_hi   = wt_lo + 768 * 256;
  short* wpt_lo   = wpt_hi + 256 * 256;

  k_pre<<<dim3(288), dim3(256), 0, stream>>>(w_qkv, w_proj, da_prior,
                                             wt_hi, wt_lo, wpt_hi, wpt_lo, ws_pp);
  k_prep_ln<<<dim3(Bn * Nn), dim3(256), 0, stream>>>(node_embeds, edge_embeds, ws_pp,
                                                     gamma, beta, ln_hi, ln_lo);
  k_qkv_mfma<<<dim3(64, 12), dim3(256), 0, stream>>>(ln_hi, ln_lo, wt_hi, wt_lo,
                                                     q_hi, q_lo, k_hi, k_lo,
                                                     vt_hi, vt_lo);
  k_attn_core<<<dim3(Bn * Hn * 16 * 2), dim3(256), 0, stream>>>(
      q_hi, q_lo, k_hi, k_lo, vt_hi, vt_lo, edge_embeds, w_expand, b_expand,
      o_part, l_part);
  k_edge_mfma<<<dim3(Bn * 16 * 16), dim3(256), 0, stream>>>(
      q_hi, q_lo, k_hi, k_lo, edge_embeds, l_part, w_expand, b_expand,
      w_reduce, b_reduce, out_edge, pl_part, pwe_part);
  k_proj_mfma<<<dim3(64, 4), dim3(256), 0, stream>>>(o_part, l_part, pl_part,
                                                     pwe_part, w_fc, b_fc,
                                                     wpt_hi, wpt_lo, b_proj,
                                                     out_node);
}